// Round 2
// baseline (53.451 us; speedup 1.0000x reference)
//
#include <hip/hip_runtime.h>
#include <hip/hip_bf16.h>

#define BATCH 16
#define CHAN  256
#define HW    16384
#define NCLS  6
#define CPB   4   // channels per block

// One block per (b, channel-group-of-4). 256 threads, 64 pixels/thread as
// 16 iterations of int4 labels + 4x float4 (one per channel). Per-class
// compares and counts computed ONCE per pixel, shared across the 4 channels.
__global__ __launch_bounds__(256)
void gt2center_kernel(const float* __restrict__ x,
                      const int*   __restrict__ gt,
                      float*       __restrict__ out) {
    const int blk = blockIdx.x;              // b * (CHAN/CPB) + cg
    const int b   = blk >> 6;                // CHAN/CPB == 64
    const int c0  = (blk & 63) * CPB;
    const float* __restrict__ xp = x  + (size_t)(b * CHAN + c0) * HW;
    const int*   __restrict__ gp = gt + (size_t)b * HW;
    const int t = threadIdx.x;

    float s[CPB][NCLS];
    int   cnt[NCLS];
#pragma unroll
    for (int j = 0; j < CPB; ++j)
#pragma unroll
        for (int k = 0; k < NCLS; ++k) s[j][k] = 0.0f;
#pragma unroll
    for (int k = 0; k < NCLS; ++k) cnt[k] = 0;

#pragma unroll 4
    for (int i = 0; i < 16; ++i) {
        const int n = i * 1024 + t * 4;
        const int4 L = *reinterpret_cast<const int4*>(gp + n);
        float4 v[CPB];
#pragma unroll
        for (int j = 0; j < CPB; ++j)
            v[j] = *reinterpret_cast<const float4*>(xp + (size_t)j * HW + n);
#pragma unroll
        for (int k = 0; k < NCLS; ++k) {
            const bool mx = (L.x == k);
            const bool my = (L.y == k);
            const bool mz = (L.z == k);
            const bool mw = (L.w == k);
            cnt[k] += (int)mx + (int)my + (int)mz + (int)mw;
#pragma unroll
            for (int j = 0; j < CPB; ++j) {
                s[j][k] += mx ? v[j].x : 0.0f;
                s[j][k] += my ? v[j].y : 0.0f;
                s[j][k] += mz ? v[j].z : 0.0f;
                s[j][k] += mw ? v[j].w : 0.0f;
            }
        }
    }

    // 64-lane butterfly reduce
#pragma unroll
    for (int off = 32; off >= 1; off >>= 1) {
#pragma unroll
        for (int k = 0; k < NCLS; ++k) {
            cnt[k] += __shfl_xor(cnt[k], off, 64);
#pragma unroll
            for (int j = 0; j < CPB; ++j)
                s[j][k] += __shfl_xor(s[j][k], off, 64);
        }
    }

    __shared__ float ls[4][CPB][NCLS];
    __shared__ int   lc[4][NCLS];
    const int wave = t >> 6, lane = t & 63;
    if (lane == 0) {
#pragma unroll
        for (int k = 0; k < NCLS; ++k) {
            lc[wave][k] = cnt[k];
#pragma unroll
            for (int j = 0; j < CPB; ++j) ls[wave][j][k] = s[j][k];
        }
    }
    __syncthreads();

    if (t < CPB * NCLS) {
        const int j = t / NCLS;          // channel within group
        const int k = t % NCLS;          // class
        const float ssum = ls[0][j][k] + ls[1][j][k] + ls[2][j][k] + ls[3][j][k];
        const int   csum = lc[0][k] + lc[1][k] + lc[2][k] + lc[3][k];
        const float d = (csum > 0) ? (float)csum : 1.0f;
        out[((size_t)b * NCLS + k) * CHAN + (c0 + j)] = ssum / d;
    }
}

extern "C" void kernel_launch(void* const* d_in, const int* in_sizes, int n_in,
                              void* d_out, int out_size, void* d_ws, size_t ws_size,
                              hipStream_t stream) {
    const float* x   = (const float*)d_in[0];
    const int*   gt  = (const int*)d_in[1];
    float*       out = (float*)d_out;
    gt2center_kernel<<<BATCH * (CHAN / CPB), 256, 0, stream>>>(x, gt, out);
}